// Round 1
// baseline (559.226 us; speedup 1.0000x reference)
//
#include <hip/hip_runtime.h>

#define NROWS 65536
#define DIM   256
#define KCB   1024
#define BM    64      // rows per block
#define BKT   64      // codes per tile
#define DCH   32      // d-chunk staged per round
#define ZST   68      // Zs row stride (pad: float4-aligned, spreads banks)
#define CST   68

// ---------------- prep: codebook norms (fp64->fp32) + zero loss accum ----------------
__global__ __launch_bounds__(256) void prep_kernel(const float* __restrict__ cb,
                                                   float* __restrict__ cnorm,
                                                   double* __restrict__ loss_acc) {
  int k = blockIdx.x * 256 + threadIdx.x;
  if (k == 0) *loss_acc = 0.0;
  if (k < KCB) {
    const float4* row = reinterpret_cast<const float4*>(cb + (size_t)k * DIM);
    double s = 0.0;
#pragma unroll 8
    for (int i = 0; i < DIM / 4; ++i) {
      float4 v = row[i];
      s += (double)v.x * v.x + (double)v.y * v.y + (double)v.z * v.z + (double)v.w * v.w;
    }
    cnorm[k] = (float)s;
  }
}

// ---------------- main: fused distances + argmin + quantized write ----------------
__global__ __launch_bounds__(256, 2) void vq_main(const float* __restrict__ z,
                                                  const float* __restrict__ cb,
                                                  const float* __restrict__ cnorm,
                                                  float* __restrict__ out_q,
                                                  float* __restrict__ out_idx,
                                                  double* __restrict__ loss_acc) {
  __shared__ float  Zs[DIM * ZST];   // 69632 B, Zs[d*ZST + m]
  __shared__ float  Cs[DCH * CST];   // 8704 B,  Cs[dd*CST + n]
  __shared__ float  af[BM];
  __shared__ float  cn_s[BKT];
  __shared__ int    idx_s[BM];
  __shared__ double lred[16];

  const int t  = threadIdx.x;
  const int r0 = blockIdx.x * BM;
  const int tx = t & 15;   // code group (4 codes each)
  const int ty = t >> 4;   // row group  (4 rows each)

  // ---- stage Z tile transposed: Zs[d][m] ----
  {
    const int m  = t >> 2;           // row 0..63
    const int qd = (t & 3) * 64;     // d-quarter
    const float4* src = reinterpret_cast<const float4*>(z + (size_t)(r0 + m) * DIM + qd);
#pragma unroll
    for (int i = 0; i < 16; ++i) {
      float4 v = src[i];
      int d = qd + i * 4;
      Zs[(d + 0) * ZST + m] = v.x;
      Zs[(d + 1) * ZST + m] = v.y;
      Zs[(d + 2) * ZST + m] = v.z;
      Zs[(d + 3) * ZST + m] = v.w;
    }
  }
  __syncthreads();

  // ---- row norms A[m] (fp64 exact -> fp32, mimics numpy scale) ----
  {
    const int m  = t >> 2;
    const int qd = (t & 3) * 64;
    double s = 0.0;
#pragma unroll 8
    for (int i = 0; i < 64; ++i) {
      float zv = Zs[(qd + i) * ZST + m];
      s += (double)zv * zv;
    }
    s += __shfl_xor(s, 1);
    s += __shfl_xor(s, 2);
    if ((t & 3) == 0) af[m] = (float)s;
  }
  __syncthreads();

  float afr[4];
#pragma unroll
  for (int j = 0; j < 4; ++j) afr[j] = af[ty * 4 + j];

  float minv[4];
  int   mini[4];
#pragma unroll
  for (int j = 0; j < 4; ++j) { minv[j] = 3.4e38f; mini[j] = 0; }

  for (int kt = 0; kt < KCB / BKT; ++kt) {
    const int k0 = kt * BKT;
    float acc[4][4];
#pragma unroll
    for (int j = 0; j < 4; ++j)
#pragma unroll
      for (int c = 0; c < 4; ++c) acc[j][c] = 0.f;

    for (int d0 = 0; d0 < DIM; d0 += DCH) {
      __syncthreads();
      if (d0 == 0 && t < BKT) cn_s[t] = cnorm[k0 + t];
      // stage Cs[dd][n]: 64 codes x 32 d, transposed
#pragma unroll
      for (int r = 0; r < 2; ++r) {
        int g  = t + r * 256;
        int n  = g >> 3;
        int f4 = g & 7;
        float4 v = *reinterpret_cast<const float4*>(cb + (size_t)(k0 + n) * DIM + d0 + f4 * 4);
        int dd = f4 * 4;
        Cs[(dd + 0) * CST + n] = v.x;
        Cs[(dd + 1) * CST + n] = v.y;
        Cs[(dd + 2) * CST + n] = v.z;
        Cs[(dd + 3) * CST + n] = v.w;
      }
      __syncthreads();
#pragma unroll
      for (int dd = 0; dd < DCH; ++dd) {
        float4 a = *reinterpret_cast<const float4*>(&Zs[(d0 + dd) * ZST + ty * 4]);
        float4 b = *reinterpret_cast<const float4*>(&Cs[dd * CST + tx * 4]);
        acc[0][0] = fmaf(a.x, b.x, acc[0][0]);
        acc[0][1] = fmaf(a.x, b.y, acc[0][1]);
        acc[0][2] = fmaf(a.x, b.z, acc[0][2]);
        acc[0][3] = fmaf(a.x, b.w, acc[0][3]);
        acc[1][0] = fmaf(a.y, b.x, acc[1][0]);
        acc[1][1] = fmaf(a.y, b.y, acc[1][1]);
        acc[1][2] = fmaf(a.y, b.z, acc[1][2]);
        acc[1][3] = fmaf(a.y, b.w, acc[1][3]);
        acc[2][0] = fmaf(a.z, b.x, acc[2][0]);
        acc[2][1] = fmaf(a.z, b.y, acc[2][1]);
        acc[2][2] = fmaf(a.z, b.z, acc[2][2]);
        acc[2][3] = fmaf(a.z, b.w, acc[2][3]);
        acc[3][0] = fmaf(a.w, b.x, acc[3][0]);
        acc[3][1] = fmaf(a.w, b.y, acc[3][1]);
        acc[3][2] = fmaf(a.w, b.z, acc[3][2]);
        acc[3][3] = fmaf(a.w, b.w, acc[3][3]);
      }
    }
    // finalize tile: t2 = fl(fl(A - 2*dot) + cnorm), numpy-rounding-compatible
#pragma unroll
    for (int c = 0; c < 4; ++c) {
      float cn = cn_s[tx * 4 + c];
      int   kb = k0 + tx * 4 + c;
#pragma unroll
      for (int j = 0; j < 4; ++j) {
        float t1 = fmaf(-2.0f, acc[j][c], afr[j]);  // 2*dot exact => single rounding, == fl(A-2B)
        float t2 = t1 + cn;
        if (t2 < minv[j]) { minv[j] = t2; mini[j] = kb; }  // strict < keeps lowest index
      }
    }
  }

  // ---- cross-lane argmin over tx (16 lanes), lowest-index tie-break ----
#pragma unroll
  for (int s = 1; s < 16; s <<= 1) {
#pragma unroll
    for (int j = 0; j < 4; ++j) {
      float ov = __shfl_xor(minv[j], s);
      int   oi = __shfl_xor(mini[j], s);
      if (ov < minv[j] || (ov == minv[j] && oi < mini[j])) { minv[j] = ov; mini[j] = oi; }
    }
  }

  if (tx == 0) {
    double lp = 0.0;
#pragma unroll
    for (int j = 0; j < 4; ++j) {
      int m = ty * 4 + j;
      idx_s[m] = mini[j];
      out_idx[r0 + m] = (float)mini[j];
      lp += (double)minv[j];   // minv = ||z-c||^2 for chosen code
    }
    lred[ty] = lp;
  }
  __syncthreads();
  if (t == 0) {
    double s = 0.0;
    for (int i = 0; i < 16; ++i) s += lred[i];
    atomicAdd(loss_acc, s);
  }

  // ---- epilogue: quantized = z + (c - z), straight-through values ----
  for (int m = 0; m < BM; ++m) {
    int   ki = idx_s[m];
    float zv = Zs[t * ZST + m];
    float cv = cb[(size_t)ki * DIM + t];
    out_q[(size_t)(r0 + m) * DIM + t] = zv + (cv - zv);
  }
}

// ---------------- finalize losses ----------------
__global__ void finalize_kernel(const double* __restrict__ loss_acc,
                                float* __restrict__ out_losses) {
  double mse = *loss_acc / ((double)NROWS * (double)DIM);
  out_losses[0] = (float)(0.25 * mse);  // commitment
  out_losses[1] = (float)mse;           // embedding
}

extern "C" void kernel_launch(void* const* d_in, const int* in_sizes, int n_in,
                              void* d_out, int out_size, void* d_ws, size_t ws_size,
                              hipStream_t stream) {
  const float* z  = (const float*)d_in[0];
  const float* cb = (const float*)d_in[1];
  float* out = (float*)d_out;

  float*  cnorm    = (float*)d_ws;
  double* loss_acc = (double*)((char*)d_ws + 4096);

  float* out_q      = out;                       // 16777216
  float* out_losses = out + 16777216;            // 2 scalars
  float* out_idx    = out + 16777218;            // 65536

  prep_kernel<<<4, 256, 0, stream>>>(cb, cnorm, loss_acc);
  vq_main<<<NROWS / BM, 256, 0, stream>>>(z, cb, cnorm, out_q, out_idx, loss_acc);
  finalize_kernel<<<1, 1, 0, stream>>>(loss_acc, out_losses);
}

// Round 2
// 505.673 us; speedup vs baseline: 1.1059x; 1.1059x over previous
//
#include <hip/hip_runtime.h>

#define NROWS 65536
#define DIM   256
#define KCB   1024
#define DELTA 0.05f

typedef __attribute__((ext_vector_type(8))) short v8s;
typedef __attribute__((ext_vector_type(4))) float v4f;
typedef __attribute__((ext_vector_type(4))) int   v4i;

__device__ __forceinline__ unsigned short bfr(float x) {
  unsigned u = __float_as_uint(x);
  u += 0x7fffu + ((u >> 16) & 1u);   // RNE to bf16
  return (unsigned short)(u >> 16);
}
__device__ __forceinline__ unsigned pk2(float a, float b) {
  return (unsigned)bfr(a) | ((unsigned)bfr(b) << 16);
}
__device__ __forceinline__ v4i pk8(float4 a, float4 b) {
  v4i r; r.x = (int)pk2(a.x,a.y); r.y = (int)pk2(a.z,a.w);
  r.z = (int)pk2(b.x,b.y); r.w = (int)pk2(b.z,b.w);
  return r;
}

// ---------------- prep: codebook norms (fp64->fp32), zero accumulators ----------------
__global__ __launch_bounds__(256) void prep_kernel(const float* __restrict__ cb,
                                                   float* __restrict__ cnorm,
                                                   double* __restrict__ loss_acc,
                                                   int* __restrict__ cnt) {
  int k = blockIdx.x * 256 + threadIdx.x;
  if (k == 0) { *loss_acc = 0.0; *cnt = 0; }
  if (k < KCB) {
    const float4* row = reinterpret_cast<const float4*>(cb + (size_t)k * DIM);
    double s = 0.0;
#pragma unroll 8
    for (int i = 0; i < DIM / 4; ++i) {
      float4 v = row[i];
      s += (double)v.x * v.x + (double)v.y * v.y + (double)v.z * v.z + (double)v.w * v.w;
    }
    cnorm[k] = (float)s;
  }
}

// ---------------- stage 1: bf16 MFMA screening, argmin + margin flag ----------------
// block: 256 thr (4 waves), tile 64 rows x 128 codes per pass, 8 passes over 1024 codes.
// Zs resident [64][256] bf16, Cs double-buffered [128][64] bf16, both XOR-swizzled.
__global__ __launch_bounds__(256, 2) void vq_mfma(
    const float* __restrict__ z, const float* __restrict__ cb,
    const float* __restrict__ cnw, int* __restrict__ idx_arr,
    int* __restrict__ list, int* __restrict__ cnt) {
  __shared__ __align__(16) short Zs[64 * 256];
  __shared__ __align__(16) short Cs[2][128 * 64];
  __shared__ float Sm1[2][64], Sm2[2][64];
  __shared__ int   Si1[2][64];

  const int t = threadIdx.x;
  const int l = t & 63;
  const int w = t >> 6;
  const int l15 = l & 15, lhi = l >> 4;
  const int wm = (w >> 1) * 32, wn = (w & 1) * 64;
  const int r0 = blockIdx.x * 64;

  // stage Z: 64 rows x 256, fp32 -> bf16, swizzle k bits 3-5 by (row&7)
#pragma unroll
  for (int p = 0; p < 8; ++p) {
    int u = t + p * 256;
    int row = u >> 5, k8 = u & 31;
    const float4* s = (const float4*)(z + (size_t)(r0 + row) * DIM + k8 * 8);
    float4 a = s[0], b = s[1];
    *(v4i*)(Zs + row * 256 + ((k8 * 8) ^ ((row & 7) << 3))) = pk8(a, b);
  }

  int arow[2], aoff[2], axr[2];
#pragma unroll
  for (int mf = 0; mf < 2; ++mf) {
    arow[mf] = wm + mf * 16 + l15;
    aoff[mf] = arow[mf] * 256;
    axr[mf] = (arow[mf] & 7) << 3;
  }
  int bcode[4], boff[4], bxr[4];
#pragma unroll
  for (int nf = 0; nf < 4; ++nf) {
    bcode[nf] = wn + nf * 16 + l15;
    boff[nf] = bcode[nf] * 64;
    bxr[nf] = (bcode[nf] & 7) << 3;
  }

  float m1[8], m2[8]; int i1[8];
#pragma unroll
  for (int sl = 0; sl < 8; ++sl) { m1[sl] = 3.0e38f; m2[sl] = 3.0e38f; i1[sl] = 0; }

  for (int nt = 0; nt < 8; ++nt) {
    float cnv[4];
#pragma unroll
    for (int nf = 0; nf < 4; ++nf) cnv[nf] = cnw[nt * 128 + bcode[nf]];

    v4f acc[2][4];
#pragma unroll
    for (int mf = 0; mf < 2; ++mf)
#pragma unroll
      for (int nf = 0; nf < 4; ++nf) acc[mf][nf] = (v4f){0.f, 0.f, 0.f, 0.f};

    // stage chunk kc=0 into buf 0
#pragma unroll
    for (int p = 0; p < 4; ++p) {
      int u = t + p * 256;
      int code = u >> 3, k8 = u & 7;
      const float4* s = (const float4*)(cb + (size_t)(nt * 128 + code) * DIM + k8 * 8);
      float4 a = s[0], b = s[1];
      *(v4i*)(Cs[0] + code * 64 + ((k8 * 8) ^ ((code & 7) << 3))) = pk8(a, b);
    }
    __syncthreads();

    for (int kc = 0; kc < 4; ++kc) {
      int cur = kc & 1;
      if (kc < 3) {
        int nxt = cur ^ 1;
#pragma unroll
        for (int p = 0; p < 4; ++p) {
          int u = t + p * 256;
          int code = u >> 3, k8 = u & 7;
          const float4* s = (const float4*)(cb + (size_t)(nt * 128 + code) * DIM + (kc + 1) * 64 + k8 * 8);
          float4 a = s[0], b = s[1];
          *(v4i*)(Cs[nxt] + code * 64 + ((k8 * 8) ^ ((code & 7) << 3))) = pk8(a, b);
        }
      }
#pragma unroll
      for (int ks = 0; ks < 2; ++ks) {
        int ka = kc * 64 + ks * 32 + lhi * 8;
        int kb = ks * 32 + lhi * 8;
        v8s a[2], b[4];
#pragma unroll
        for (int mf = 0; mf < 2; ++mf)
          a[mf] = *(const v8s*)(Zs + aoff[mf] + (ka ^ axr[mf]));
#pragma unroll
        for (int nf = 0; nf < 4; ++nf)
          b[nf] = *(const v8s*)(Cs[cur] + boff[nf] + (kb ^ bxr[nf]));
#pragma unroll
        for (int mf = 0; mf < 2; ++mf)
#pragma unroll
          for (int nf = 0; nf < 4; ++nf)
            acc[mf][nf] = __builtin_amdgcn_mfma_f32_16x16x32_bf16(a[mf], b[nf], acc[mf][nf], 0, 0, 0);
      }
      __syncthreads();
    }

    // running (min1, idx1, min2) update; ties -> gap 0 -> rescue
#pragma unroll
    for (int mf = 0; mf < 2; ++mf)
#pragma unroll
      for (int nf = 0; nf < 4; ++nf) {
        int code = nt * 128 + bcode[nf];
#pragma unroll
        for (int r = 0; r < 4; ++r) {
          float s = fmaf(-2.f, acc[mf][nf][r], cnv[nf]);
          int sl = mf * 4 + r;
          bool lt = s < m1[sl];
          m2[sl] = lt ? m1[sl] : fminf(m2[sl], s);
          i1[sl] = lt ? code : i1[sl];
          m1[sl] = lt ? s : m1[sl];
        }
      }
  }

  // cross-lane argmin over the 16 code-lanes (same rows per group)
#pragma unroll
  for (int off = 1; off < 16; off <<= 1) {
#pragma unroll
    for (int sl = 0; sl < 8; ++sl) {
      float o1 = __shfl_xor(m1[sl], off);
      int   oi = __shfl_xor(i1[sl], off);
      float o2 = __shfl_xor(m2[sl], off);
      bool bb = (o1 < m1[sl]) || (o1 == m1[sl] && oi < i1[sl]);
      float hi = fmaxf(m1[sl], o1);
      m2[sl] = fminf(hi, fminf(m2[sl], o2));
      m1[sl] = bb ? o1 : m1[sl];
      i1[sl] = bb ? oi : i1[sl];
    }
  }

  if (l15 == 0) {
#pragma unroll
    for (int sl = 0; sl < 8; ++sl) {
      int row = wm + (sl >> 2) * 16 + lhi * 4 + (sl & 3);
      Sm1[w & 1][row] = m1[sl];
      Sm2[w & 1][row] = m2[sl];
      Si1[w & 1][row] = i1[sl];
    }
  }
  __syncthreads();
  if (t < 64) {
    float a1 = Sm1[0][t], b1 = Sm1[1][t];
    float a2 = Sm2[0][t], b2 = Sm2[1][t];
    int   ai = Si1[0][t], bi = Si1[1][t];
    bool bb = (b1 < a1) || (b1 == a1 && bi < ai);
    float hi = fmaxf(a1, b1);
    float mm2 = fminf(hi, fminf(a2, b2));
    float mm1 = bb ? b1 : a1;
    int   ii = bb ? bi : ai;
    idx_arr[r0 + t] = ii;
    if (mm2 - mm1 < DELTA) {
      int p = atomicAdd(cnt, 1);
      list[p] = r0 + t;
    }
  }
}

// ---------------- rescue: exact fp32 recompute (round-1-identical rounding) ----------------
__global__ __launch_bounds__(256) void vq_rescue(
    const float* __restrict__ z, const float* __restrict__ cb,
    const float* __restrict__ cnw, const int* __restrict__ list,
    const int* __restrict__ cnt, int* __restrict__ idx_arr) {
  __shared__ float Zr[16 * 256];
  __shared__ float Csr[64 * 260];
  __shared__ float Ars[16];
  __shared__ int   Sgr[16];

  const int t = threadIdx.x;
  const int n = *cnt;
  const int cl = t & 63, w = t >> 6;

  for (int base = blockIdx.x * 16; base < n; base += gridDim.x * 16) {
    int nr = min(16, n - base);
    __syncthreads();
    if (t < 16) Sgr[t] = (t < nr) ? list[base + t] : 0;
    __syncthreads();
    {
      int i = t >> 4, seg = t & 15;
      if (i < nr) {
        const float4* s = (const float4*)(z + (size_t)Sgr[i] * DIM + seg * 16);
        float4* d = (float4*)(Zr + i * 256 + seg * 16);
#pragma unroll
        for (int p = 0; p < 4; ++p) d[p] = s[p];
      }
    }
    __syncthreads();
    // fp64 row norms, exact round-1 tree: ((q0+q1)+(q2+q3)) -> fp32
    if (t < 64) {
      int row = t >> 2, ch = t & 3;
      double s = 0.0;
      if (row < nr) {
        const float* zz = Zr + row * 256 + ch * 64;
        for (int i = 0; i < 64; ++i) { float v = zz[i]; s += (double)v * v; }
      }
      s += __shfl_xor(s, 1);
      s += __shfl_xor(s, 2);
      if (ch == 0) Ars[row] = (float)s;
    }
    __syncthreads();
    float ar[4];
#pragma unroll
    for (int j = 0; j < 4; ++j) ar[j] = Ars[w + 4 * j];

    float mv[4]; int mi[4];
#pragma unroll
    for (int j = 0; j < 4; ++j) { mv[j] = 3.0e38f; mi[j] = 0; }

    for (int ct = 0; ct < 16; ++ct) {
      __syncthreads();
#pragma unroll
      for (int p = 0; p < 16; ++p) {
        int u = t + p * 256;
        int code = u >> 6, f4i = u & 63;
        const float4* s = (const float4*)(cb + (size_t)(ct * 64 + code) * DIM + f4i * 4);
        *(float4*)(Csr + code * 260 + f4i * 4) = s[0];
      }
      __syncthreads();
      float cn = cnw[ct * 64 + cl];
      float acc0 = 0.f, acc1 = 0.f, acc2 = 0.f, acc3 = 0.f;
      for (int d4 = 0; d4 < 64; ++d4) {
        float4 c4 = *(const float4*)(Csr + cl * 260 + d4 * 4);
        float4 z0 = *(const float4*)(Zr + (w + 0) * 256 + d4 * 4);
        float4 z1 = *(const float4*)(Zr + (w + 4) * 256 + d4 * 4);
        float4 z2 = *(const float4*)(Zr + (w + 8) * 256 + d4 * 4);
        float4 z3 = *(const float4*)(Zr + (w + 12) * 256 + d4 * 4);
        acc0 = fmaf(z0.x, c4.x, acc0); acc0 = fmaf(z0.y, c4.y, acc0);
        acc0 = fmaf(z0.z, c4.z, acc0); acc0 = fmaf(z0.w, c4.w, acc0);
        acc1 = fmaf(z1.x, c4.x, acc1); acc1 = fmaf(z1.y, c4.y, acc1);
        acc1 = fmaf(z1.z, c4.z, acc1); acc1 = fmaf(z1.w, c4.w, acc1);
        acc2 = fmaf(z2.x, c4.x, acc2); acc2 = fmaf(z2.y, c4.y, acc2);
        acc2 = fmaf(z2.z, c4.z, acc2); acc2 = fmaf(z2.w, c4.w, acc2);
        acc3 = fmaf(z3.x, c4.x, acc3); acc3 = fmaf(z3.y, c4.y, acc3);
        acc3 = fmaf(z3.z, c4.z, acc3); acc3 = fmaf(z3.w, c4.w, acc3);
      }
      int code = ct * 64 + cl;
      float accs[4] = {acc0, acc1, acc2, acc3};
#pragma unroll
      for (int j = 0; j < 4; ++j) {
        float t1 = fmaf(-2.f, accs[j], ar[j]);
        float t2 = t1 + cn;
        if (t2 < mv[j]) { mv[j] = t2; mi[j] = code; }
      }
    }
#pragma unroll
    for (int off = 1; off < 64; off <<= 1) {
#pragma unroll
      for (int j = 0; j < 4; ++j) {
        float ov = __shfl_xor(mv[j], off);
        int   oi = __shfl_xor(mi[j], off);
        if (ov < mv[j] || (ov == mv[j] && oi < mi[j])) { mv[j] = ov; mi[j] = oi; }
      }
    }
    if (cl == 0) {
#pragma unroll
      for (int j = 0; j < 4; ++j) {
        int row = w + 4 * j;
        if (row < nr) idx_arr[Sgr[row]] = mi[j];
      }
    }
  }
}

// ---------------- epilogue: gather, straight-through write, loss ----------------
__global__ __launch_bounds__(256) void vq_epilogue(
    const float* __restrict__ z, const float* __restrict__ cb,
    const int* __restrict__ idx_arr, float* __restrict__ out_q,
    float* __restrict__ out_idx, double* __restrict__ loss_acc) {
  int g = blockIdx.x * 256 + threadIdx.x;
  int row = g >> 4, seg = g & 15;
  int ki = idx_arr[row];
  const float4* zr = (const float4*)(z + (size_t)row * DIM) + seg * 4;
  const float4* cr = (const float4*)(cb + (size_t)ki * DIM) + seg * 4;
  float4* qr = (float4*)(out_q + (size_t)row * DIM) + seg * 4;
  double ls = 0.0;
#pragma unroll
  for (int p = 0; p < 4; ++p) {
    float4 zv = zr[p], cv = cr[p];
    float dx = cv.x - zv.x, dy = cv.y - zv.y, dz = cv.z - zv.z, dw = cv.w - zv.w;
    float4 o; o.x = zv.x + dx; o.y = zv.y + dy; o.z = zv.z + dz; o.w = zv.w + dw;
    qr[p] = o;
    ls += (double)dx * dx + (double)dy * dy + (double)dz * dz + (double)dw * dw;
  }
  if (seg == 0) out_idx[row] = (float)ki;
#pragma unroll
  for (int off = 1; off < 64; off <<= 1) ls += __shfl_xor(ls, off);
  if ((threadIdx.x & 63) == 0) atomicAdd(loss_acc, ls);
}

// ---------------- finalize losses ----------------
__global__ void finalize_kernel(const double* __restrict__ loss_acc,
                                float* __restrict__ out_losses) {
  double mse = *loss_acc / ((double)NROWS * (double)DIM);
  out_losses[0] = (float)(0.25 * mse);  // commitment
  out_losses[1] = (float)mse;           // embedding
}

extern "C" void kernel_launch(void* const* d_in, const int* in_sizes, int n_in,
                              void* d_out, int out_size, void* d_ws, size_t ws_size,
                              hipStream_t stream) {
  const float* z  = (const float*)d_in[0];
  const float* cb = (const float*)d_in[1];
  float* out = (float*)d_out;

  char* ws = (char*)d_ws;
  double* loss_acc = (double*)(ws + 0);
  int*    cnt      = (int*)(ws + 8);
  float*  cnorm    = (float*)(ws + 16);
  int*    idx_arr  = (int*)(ws + 8192);
  int*    list     = (int*)(ws + 8192 + 262144);

  float* out_q      = out;             // 16777216
  float* out_losses = out + 16777216;  // 2
  float* out_idx    = out + 16777218;  // 65536

  prep_kernel<<<4, 256, 0, stream>>>(cb, cnorm, loss_acc, cnt);
  vq_mfma<<<NROWS / 64, 256, 0, stream>>>(z, cb, cnorm, idx_arr, list, cnt);
  vq_rescue<<<256, 256, 0, stream>>>(z, cb, cnorm, list, cnt, idx_arr);
  vq_epilogue<<<NROWS * 16 / 256, 256, 0, stream>>>(z, cb, idx_arr, out_q, out_idx, loss_acc);
  finalize_kernel<<<1, 1, 0, stream>>>(loss_acc, out_losses);
}

// Round 3
// 290.588 us; speedup vs baseline: 1.9245x; 1.7402x over previous
//
#include <hip/hip_runtime.h>

#define NROWS 65536
#define DIM   256
#define KCB   1024
#define DELTA 0.05f

typedef __attribute__((ext_vector_type(8))) short v8s;
typedef __attribute__((ext_vector_type(4))) float v4f;
typedef __attribute__((ext_vector_type(4))) int   v4i;

__device__ __forceinline__ unsigned short bfr(float x) {
  unsigned u = __float_as_uint(x);
  u += 0x7fffu + ((u >> 16) & 1u);   // RNE to bf16
  return (unsigned short)(u >> 16);
}
__device__ __forceinline__ unsigned pk2(float a, float b) {
  return (unsigned)bfr(a) | ((unsigned)bfr(b) << 16);
}
__device__ __forceinline__ v4i pk8(float4 a, float4 b) {
  v4i r; r.x = (int)pk2(a.x,a.y); r.y = (int)pk2(a.z,a.w);
  r.z = (int)pk2(b.x,b.y); r.w = (int)pk2(b.z,b.w);
  return r;
}
__device__ __forceinline__ void gld16(const void* g, void* l) {
  __builtin_amdgcn_global_load_lds(
      (const __attribute__((address_space(1))) unsigned int*)g,
      (__attribute__((address_space(3))) unsigned int*)l, 16, 0, 0);
}

// ---------------- prep: codebook norms + bf16 swizzled-LDS-image codebook ----------------
// cbswz layout: [chunk g=nt*4+kc : 32][code c=0..127][k=0..63] bf16, with
// k-position swizzled: pos = (k8*8) ^ ((c&7)<<3) at 8-element granularity.
__global__ __launch_bounds__(256) void prep_kernel(const float* __restrict__ cb,
                                                   float* __restrict__ cnorm,
                                                   unsigned short* __restrict__ cbswz,
                                                   int* __restrict__ cnt) {
  int g = blockIdx.x * 256 + threadIdx.x;   // 4096 threads: code k = g>>2, quarter q = g&3
  if (g == 0) *cnt = 0;
  int k = g >> 2, q = g & 3;
  int nt = k >> 7, c = k & 127;
  const float4* row = reinterpret_cast<const float4*>(cb + (size_t)k * DIM) + q * 16;
  unsigned short* dst = cbswz + (size_t)((nt * 4 + q) * 128 + c) * 64;
  int xr = (c & 7) << 3;
  double s = 0.0;
#pragma unroll
  for (int i = 0; i < 8; ++i) {
    float4 a = row[2 * i], b = row[2 * i + 1];
    s += (double)a.x * a.x + (double)a.y * a.y + (double)a.z * a.z + (double)a.w * a.w;
    s += (double)b.x * b.x + (double)b.y * b.y + (double)b.z * b.z + (double)b.w * b.w;
    *(v4i*)(dst + ((i * 8) ^ xr)) = pk8(a, b);
  }
  s += __shfl_xor(s, 1);
  s += __shfl_xor(s, 2);
  if (q == 0) cnorm[k] = (float)s;
}

// ---------------- stage 1: bf16 MFMA screening, argmin + margin flag ----------------
// 256 thr (4 waves), tile 64 rows x 128 codes x 8 passes. Zs resident, Cs
// double-buffered via global_load_lds (pre-swizzled global image), 2-phase.
__global__ __launch_bounds__(256, 2) void vq_mfma(
    const float* __restrict__ z, const unsigned short* __restrict__ cbswz,
    const float* __restrict__ cnw, int* __restrict__ idx_arr,
    int* __restrict__ list, int* __restrict__ cnt) {
  __shared__ __align__(16) short Zs[64 * 256];
  __shared__ __align__(16) short Cs[2][128 * 64];
  __shared__ float Sm1[2][64], Sm2[2][64];
  __shared__ int   Si1[2][64];

  const int t = threadIdx.x;
  const int l = t & 63;
  const int w = t >> 6;
  const int l15 = l & 15, lhi = l >> 4;
  const int wm = (w >> 1) * 32, wn = (w & 1) * 64;
  const int r0 = blockIdx.x * 64;

  // stage Z: 64 rows x 256, fp32 -> bf16, swizzle k bits 3-5 by (row&7)
#pragma unroll
  for (int p = 0; p < 8; ++p) {
    int u = t + p * 256;
    int row = u >> 5, k8 = u & 31;
    const float4* s = (const float4*)(z + (size_t)(r0 + row) * DIM + k8 * 8);
    float4 a = s[0], b = s[1];
    *(v4i*)(Zs + row * 256 + ((k8 * 8) ^ ((row & 7) << 3))) = pk8(a, b);
  }

  // C-chunk stage: 16KB, 4 x 1KB glds per wave
  auto stageC = [&](int g, short* buf) {
    const char* gb = (const char*)cbswz + (size_t)g * 16384 + w * 4096 + l * 16;
    char* lb = (char*)buf + w * 4096;
#pragma unroll
    for (int j = 0; j < 4; ++j) gld16(gb + j * 1024, lb + j * 1024);
  };

  int arow[2], aoff[2], axr[2];
#pragma unroll
  for (int mf = 0; mf < 2; ++mf) {
    arow[mf] = wm + mf * 16 + l15;
    aoff[mf] = arow[mf] * 256;
    axr[mf] = (arow[mf] & 7) << 3;
  }
  int bcode[4], boff[4], bxr[4];
#pragma unroll
  for (int nf = 0; nf < 4; ++nf) {
    bcode[nf] = wn + nf * 16 + l15;
    boff[nf] = bcode[nf] * 64;
    bxr[nf] = (bcode[nf] & 7) << 3;
  }

  float m1[8], m2[8]; int i1[8];
#pragma unroll
  for (int sl = 0; sl < 8; ++sl) { m1[sl] = 3.0e38f; m2[sl] = 3.0e38f; i1[sl] = 0; }

  stageC(0, Cs[0]);
  __syncthreads();   // covers Zs writes + chunk-0 glds

  for (int nt = 0; nt < 8; ++nt) {
    float cnv[4];
#pragma unroll
    for (int nf = 0; nf < 4; ++nf) cnv[nf] = cnw[nt * 128 + bcode[nf]];

    v4f acc[2][4];
#pragma unroll
    for (int mf = 0; mf < 2; ++mf)
#pragma unroll
      for (int nf = 0; nf < 4; ++nf) acc[mf][nf] = (v4f){0.f, 0.f, 0.f, 0.f};

    for (int kc = 0; kc < 4; ++kc) {
      int g = nt * 4 + kc;
      if (g < 31) stageC(g + 1, Cs[(g + 1) & 1]);   // prefetch ∥ compute
      const short* cur = Cs[g & 1];
#pragma unroll
      for (int ks = 0; ks < 2; ++ks) {
        int ka = kc * 64 + ks * 32 + lhi * 8;
        int kb = ks * 32 + lhi * 8;
        v8s a[2], b[4];
#pragma unroll
        for (int mf = 0; mf < 2; ++mf)
          a[mf] = *(const v8s*)(Zs + aoff[mf] + (ka ^ axr[mf]));
#pragma unroll
        for (int nf = 0; nf < 4; ++nf)
          b[nf] = *(const v8s*)(cur + boff[nf] + (kb ^ bxr[nf]));
#pragma unroll
        for (int mf = 0; mf < 2; ++mf)
#pragma unroll
          for (int nf = 0; nf < 4; ++nf)
            acc[mf][nf] = __builtin_amdgcn_mfma_f32_16x16x32_bf16(a[mf], b[nf], acc[mf][nf], 0, 0, 0);
      }
      __syncthreads();   // drains glds (vmcnt0) + compute done on cur
    }

    // running (min1, idx1, min2) update
#pragma unroll
    for (int mf = 0; mf < 2; ++mf)
#pragma unroll
      for (int nf = 0; nf < 4; ++nf) {
        int code = nt * 128 + bcode[nf];
#pragma unroll
        for (int r = 0; r < 4; ++r) {
          float s = fmaf(-2.f, acc[mf][nf][r], cnv[nf]);
          int sl = mf * 4 + r;
          bool lt = s < m1[sl];
          m2[sl] = lt ? m1[sl] : fminf(m2[sl], s);
          i1[sl] = lt ? code : i1[sl];
          m1[sl] = lt ? s : m1[sl];
        }
      }
  }

  // cross-lane argmin over the 16 code-lanes
#pragma unroll
  for (int off = 1; off < 16; off <<= 1) {
#pragma unroll
    for (int sl = 0; sl < 8; ++sl) {
      float o1 = __shfl_xor(m1[sl], off);
      int   oi = __shfl_xor(i1[sl], off);
      float o2 = __shfl_xor(m2[sl], off);
      bool bb = (o1 < m1[sl]) || (o1 == m1[sl] && oi < i1[sl]);
      float hi = fmaxf(m1[sl], o1);
      m2[sl] = fminf(hi, fminf(m2[sl], o2));
      m1[sl] = bb ? o1 : m1[sl];
      i1[sl] = bb ? oi : i1[sl];
    }
  }

  if (l15 == 0) {
#pragma unroll
    for (int sl = 0; sl < 8; ++sl) {
      int row = wm + (sl >> 2) * 16 + lhi * 4 + (sl & 3);
      Sm1[w & 1][row] = m1[sl];
      Sm2[w & 1][row] = m2[sl];
      Si1[w & 1][row] = i1[sl];
    }
  }
  __syncthreads();
  if (t < 64) {
    float a1 = Sm1[0][t], b1 = Sm1[1][t];
    float a2 = Sm2[0][t], b2 = Sm2[1][t];
    int   ai = Si1[0][t], bi = Si1[1][t];
    bool bb = (b1 < a1) || (b1 == a1 && bi < ai);
    float hi = fmaxf(a1, b1);
    float mm2 = fminf(hi, fminf(a2, b2));
    float mm1 = bb ? b1 : a1;
    int   ii = bb ? bi : ai;
    idx_arr[r0 + t] = ii;
    if (mm2 - mm1 < DELTA) {
      int p = atomicAdd(cnt, 1);
      list[p] = r0 + t;
    }
  }
}

// ---------------- rescue: exact fp32 recompute (round-1-identical rounding) ----------------
__global__ __launch_bounds__(256) void vq_rescue(
    const float* __restrict__ z, const float* __restrict__ cb,
    const float* __restrict__ cnw, const int* __restrict__ list,
    const int* __restrict__ cnt, int* __restrict__ idx_arr) {
  __shared__ float Zr[16 * 256];
  __shared__ float Csr[64 * 260];
  __shared__ float Ars[16];
  __shared__ int   Sgr[16];

  const int t = threadIdx.x;
  const int n = *cnt;
  const int cl = t & 63, w = t >> 6;

  for (int base = blockIdx.x * 16; base < n; base += gridDim.x * 16) {
    int nr = min(16, n - base);
    __syncthreads();
    if (t < 16) Sgr[t] = (t < nr) ? list[base + t] : 0;
    __syncthreads();
    {
      int i = t >> 4, seg = t & 15;
      if (i < nr) {
        const float4* s = (const float4*)(z + (size_t)Sgr[i] * DIM + seg * 16);
        float4* d = (float4*)(Zr + i * 256 + seg * 16);
#pragma unroll
        for (int p = 0; p < 4; ++p) d[p] = s[p];
      }
    }
    __syncthreads();
    if (t < 64) {
      int row = t >> 2, ch = t & 3;
      double s = 0.0;
      if (row < nr) {
        const float* zz = Zr + row * 256 + ch * 64;
        for (int i = 0; i < 64; ++i) { float v = zz[i]; s += (double)v * v; }
      }
      s += __shfl_xor(s, 1);
      s += __shfl_xor(s, 2);
      if (ch == 0) Ars[row] = (float)s;
    }
    __syncthreads();
    float ar[4];
#pragma unroll
    for (int j = 0; j < 4; ++j) ar[j] = Ars[w + 4 * j];

    float mv[4]; int mi[4];
#pragma unroll
    for (int j = 0; j < 4; ++j) { mv[j] = 3.0e38f; mi[j] = 0; }

    for (int ct = 0; ct < 16; ++ct) {
      __syncthreads();
#pragma unroll
      for (int p = 0; p < 16; ++p) {
        int u = t + p * 256;
        int code = u >> 6, f4i = u & 63;
        const float4* s = (const float4*)(cb + (size_t)(ct * 64 + code) * DIM + f4i * 4);
        *(float4*)(Csr + code * 260 + f4i * 4) = s[0];
      }
      __syncthreads();
      float cn = cnw[ct * 64 + cl];
      float acc0 = 0.f, acc1 = 0.f, acc2 = 0.f, acc3 = 0.f;
      for (int d4 = 0; d4 < 64; ++d4) {
        float4 c4 = *(const float4*)(Csr + cl * 260 + d4 * 4);
        float4 z0 = *(const float4*)(Zr + (w + 0) * 256 + d4 * 4);
        float4 z1 = *(const float4*)(Zr + (w + 4) * 256 + d4 * 4);
        float4 z2 = *(const float4*)(Zr + (w + 8) * 256 + d4 * 4);
        float4 z3 = *(const float4*)(Zr + (w + 12) * 256 + d4 * 4);
        acc0 = fmaf(z0.x, c4.x, acc0); acc0 = fmaf(z0.y, c4.y, acc0);
        acc0 = fmaf(z0.z, c4.z, acc0); acc0 = fmaf(z0.w, c4.w, acc0);
        acc1 = fmaf(z1.x, c4.x, acc1); acc1 = fmaf(z1.y, c4.y, acc1);
        acc1 = fmaf(z1.z, c4.z, acc1); acc1 = fmaf(z1.w, c4.w, acc1);
        acc2 = fmaf(z2.x, c4.x, acc2); acc2 = fmaf(z2.y, c4.y, acc2);
        acc2 = fmaf(z2.z, c4.z, acc2); acc2 = fmaf(z2.w, c4.w, acc2);
        acc3 = fmaf(z3.x, c4.x, acc3); acc3 = fmaf(z3.y, c4.y, acc3);
        acc3 = fmaf(z3.z, c4.z, acc3); acc3 = fmaf(z3.w, c4.w, acc3);
      }
      int code = ct * 64 + cl;
      float accs[4] = {acc0, acc1, acc2, acc3};
#pragma unroll
      for (int j = 0; j < 4; ++j) {
        float t1 = fmaf(-2.f, accs[j], ar[j]);
        float t2 = t1 + cn;
        if (t2 < mv[j]) { mv[j] = t2; mi[j] = code; }
      }
    }
#pragma unroll
    for (int off = 1; off < 64; off <<= 1) {
#pragma unroll
      for (int j = 0; j < 4; ++j) {
        float ov = __shfl_xor(mv[j], off);
        int   oi = __shfl_xor(mi[j], off);
        if (ov < mv[j] || (ov == mv[j] && oi < mi[j])) { mv[j] = ov; mi[j] = oi; }
      }
    }
    if (cl == 0) {
#pragma unroll
      for (int j = 0; j < 4; ++j) {
        int row = w + 4 * j;
        if (row < nr) idx_arr[Sgr[row]] = mi[j];
      }
    }
  }
}

// ---------------- epilogue: gather, straight-through write, per-block loss ----------------
__global__ __launch_bounds__(256) void vq_epilogue(
    const float* __restrict__ z, const float* __restrict__ cb,
    const int* __restrict__ idx_arr, float* __restrict__ out_q,
    float* __restrict__ out_idx, double* __restrict__ partial) {
  __shared__ int idxs[16];
  __shared__ double lw[4];
  const int t = threadIdx.x;
  const int b0 = blockIdx.x * 16;   // 16 rows per block
  if (t < 16) {
    int k = idx_arr[b0 + t];
    idxs[t] = k;
    out_idx[b0 + t] = (float)k;
  }
  __syncthreads();
  const float4* zb = (const float4*)(z + (size_t)b0 * DIM);
  float4* qb = (float4*)(out_q + (size_t)b0 * DIM);
  double ls = 0.0;
#pragma unroll
  for (int p = 0; p < 4; ++p) {
    int fi = p * 256 + t;           // lane-contiguous float4 index
    int ki = idxs[fi >> 6];
    float4 zv = zb[fi];
    float4 cv = ((const float4*)(cb + (size_t)ki * DIM))[fi & 63];
    float dx = cv.x - zv.x, dy = cv.y - zv.y, dz = cv.z - zv.z, dw = cv.w - zv.w;
    float4 o; o.x = zv.x + dx; o.y = zv.y + dy; o.z = zv.z + dz; o.w = zv.w + dw;
    qb[fi] = o;
    ls += (double)dx * dx + (double)dy * dy + (double)dz * dz + (double)dw * dw;
  }
#pragma unroll
  for (int off = 1; off < 64; off <<= 1) ls += __shfl_xor(ls, off);
  if ((t & 63) == 0) lw[t >> 6] = ls;
  __syncthreads();
  if (t == 0) partial[blockIdx.x] = lw[0] + lw[1] + lw[2] + lw[3];
}

// ---------------- finalize losses ----------------
__global__ __launch_bounds__(256) void finalize_kernel(const double* __restrict__ partial,
                                                       float* __restrict__ out_losses) {
  __shared__ double lw[4];
  const int t = threadIdx.x;
  double s = 0.0;
  for (int i = t; i < 4096; i += 256) s += partial[i];
#pragma unroll
  for (int off = 1; off < 64; off <<= 1) s += __shfl_xor(s, off);
  if ((t & 63) == 0) lw[t >> 6] = s;
  __syncthreads();
  if (t == 0) {
    double mse = (lw[0] + lw[1] + lw[2] + lw[3]) / ((double)NROWS * (double)DIM);
    out_losses[0] = (float)(0.25 * mse);  // commitment
    out_losses[1] = (float)mse;           // embedding
  }
}

extern "C" void kernel_launch(void* const* d_in, const int* in_sizes, int n_in,
                              void* d_out, int out_size, void* d_ws, size_t ws_size,
                              hipStream_t stream) {
  const float* z  = (const float*)d_in[0];
  const float* cb = (const float*)d_in[1];
  float* out = (float*)d_out;

  char* ws = (char*)d_ws;
  int*            cnt     = (int*)(ws + 0);
  float*          cnorm   = (float*)(ws + 4096);
  double*         partial = (double*)(ws + 8192);            // 4096 doubles
  int*            idx_arr = (int*)(ws + 40960);              // 64K ints
  int*            list    = (int*)(ws + 40960 + 262144);     // worst-case 64K ints
  unsigned short* cbswz   = (unsigned short*)(ws + 40960 + 524288);  // 512KB

  float* out_q      = out;             // 16777216
  float* out_losses = out + 16777216;  // 2
  float* out_idx    = out + 16777218;  // 65536

  prep_kernel<<<16, 256, 0, stream>>>(cb, cnorm, cbswz, cnt);
  vq_mfma<<<NROWS / 64, 256, 0, stream>>>(z, cbswz, cnorm, idx_arr, list, cnt);
  vq_rescue<<<256, 256, 0, stream>>>(z, cb, cnorm, list, cnt, idx_arr);
  vq_epilogue<<<NROWS / 16, 256, 0, stream>>>(z, cb, idx_arr, out_q, out_idx, partial);
  finalize_kernel<<<1, 256, 0, stream>>>(partial, out_losses);
}